// Round 1
// baseline (53661.249 us; speedup 1.0000x reference)
//
#include <hip/hip_runtime.h>
#include <stdint.h>

typedef unsigned short u16;
typedef unsigned int   u32;
using bf16x8 = __attribute__((ext_vector_type(8))) short;
using f32x4  = __attribute__((ext_vector_type(4))) float;

#define T_LEN 2048
#define BATCH 32
#define FDIM  512
#define HDIM  512
#define GDIM  1536
#define WG_PER_DIR 64
#define SLICE 8            // h indices per WG
#define NROWS 24           // real gate rows per WG (3 gates x SLICE)
#define LSTR  520          // LDS row stride in u16: 1040B, 16B-aligned, 2-way-bank-free

__device__ __forceinline__ u16 f2bf(float f) {
  union { float f; u32 u; } v; v.f = f;
  u32 r = v.u + 0x7fffu + ((v.u >> 16) & 1u);
  return (u16)(r >> 16);
}

__global__ void convert_kernel(const float* __restrict__ src, u16* __restrict__ dst, int n4) {
  int i = blockIdx.x * blockDim.x + threadIdx.x;
  int stride = gridDim.x * blockDim.x;
  for (; i < n4; i += stride) {
    float4 v = ((const float4*)src)[i];
    ushort4 o;
    o.x = f2bf(v.x); o.y = f2bf(v.y); o.z = f2bf(v.z); o.w = f2bf(v.w);
    ((ushort4*)dst)[i] = o;
  }
}

__launch_bounds__(256, 1)
__global__ void gru_scan(
    const u16* __restrict__ xbf,                               // [T][B][F] bf16
    const u16* __restrict__ wihF, const u16* __restrict__ whhF, // [G][K] bf16
    const u16* __restrict__ wihR, const u16* __restrict__ whhR,
    const float* __restrict__ bihF, const float* __restrict__ bhhF,
    const float* __restrict__ bihR, const float* __restrict__ bhhR,
    const float* __restrict__ h0,                              // [2][B][H] f32
    u16* __restrict__ hbuf,                                    // [2 buf][2 dir][B][H] bf16
    float* __restrict__ out,                                   // y [T][B][2H] + states [2][B][H]
    u32* __restrict__ counters)                                // per-dir counter, 128B apart
{
  const int wg   = blockIdx.x;
  const int dir  = (wg >= WG_PER_DIR) ? 1 : 0;
  const int wgl  = wg - dir * WG_PER_DIR;
  const int hbase = wgl * SLICE;
  const int tid  = threadIdx.x;
  const int lane = tid & 63;
  const int wave = tid >> 6;
  const int mt = wave & 1;         // M (batch) tile: 2 x 16
  const int nt = wave >> 1;        // N (gate-col) tile: 2 x 16 (rows 24..31 zero-padded)

  const u16*  wih = dir ? wihR : wihF;
  const u16*  whh = dir ? whhR : whhF;
  const float* bih = dir ? bihR : bihF;
  const float* bhh = dir ? bhhR : bhhF;
  u32* cnt = counters + dir * 32;

  __shared__ u16   buf[32 * LSTR];     // staged A operand (x_t, then h_t)
  __shared__ float s_gi[32][33];
  __shared__ float s_gh[32][33];
  __shared__ float s_hold[32][SLICE];  // fp32 resident h slice
  __shared__ float s_bih[NROWS];
  __shared__ float s_bhh[NROWS];

  // ---- preload weight B-fragments into registers (stay for whole scan) ----
  bf16x8 wfi[16], wfh[16];
  {
    const int nloc = nt * 16 + (lane & 15);   // 0..31, >=24 is pad
    const int kq   = (lane >> 4) * 8;         // k sub-offset within 32-wide K step
    if (nloc < NROWS) {
      const int g = (nloc >> 3) * HDIM + hbase + (nloc & 7);  // gate*512 + h index
      const u16* pih = wih + (size_t)g * FDIM + kq;
      const u16* phh = whh + (size_t)g * HDIM + kq;
#pragma unroll
      for (int kk = 0; kk < 16; ++kk) {
        wfi[kk] = *(const bf16x8*)(pih + kk * 32);
        wfh[kk] = *(const bf16x8*)(phh + kk * 32);
      }
    } else {
      bf16x8 z = {};
#pragma unroll
      for (int kk = 0; kk < 16; ++kk) { wfi[kk] = z; wfh[kk] = z; }
    }
  }

  if (tid < NROWS) {
    const int g = (tid >> 3) * HDIM + hbase + (tid & 7);
    s_bih[tid] = bih[g];
    s_bhh[tid] = bhh[g];
  }

  // ---- init resident h slice + publish h_0 (bf16) ----
  {
    const int b = tid >> 3, hh = tid & 7;
    float v = h0[(dir * BATCH + b) * HDIM + hbase + hh];
    s_hold[b][hh] = v;
    hbuf[(size_t)dir * (BATCH * HDIM) + b * HDIM + hbase + hh] = f2bf(v);
  }
  __threadfence();
  __syncthreads();
  if (tid == 0) __hip_atomic_fetch_add(cnt, 1u, __ATOMIC_ACQ_REL, __HIP_MEMORY_SCOPE_AGENT);

  const int arow = mt * 16 + (lane & 15);
  const int koff = (lane >> 4) * 8;

  for (int t = 0; t < T_LEN; ++t) {
    // ======== phase 1: x_t staging + ih-GEMM (independent of h_t, hides sync) ========
    const int tx = dir ? (T_LEN - 1 - t) : t;
    const u16* xsrc = xbf + (size_t)tx * (BATCH * FDIM);
#pragma unroll
    for (int j = 0; j < 8; ++j) {
      const int c = tid + 256 * j;         // 2048 chunks of 16B
      const int row = c >> 6;
      const int col = (c & 63) * 8;
      *(bf16x8*)(buf + row * LSTR + col) = *(const bf16x8*)(xsrc + row * FDIM + col);
    }
    __syncthreads();

    {
      f32x4 acc = {0.f, 0.f, 0.f, 0.f};
      const u16* ab = buf + arow * LSTR + koff;
#pragma unroll
      for (int kk = 0; kk < 16; ++kk) {
        bf16x8 a = *(const bf16x8*)(ab + kk * 32);
        acc = __builtin_amdgcn_mfma_f32_16x16x32_bf16(a, wfi[kk], acc, 0, 0, 0);
      }
      const int col = nt * 16 + (lane & 15);
      const int rb  = mt * 16 + ((lane >> 4) << 2);
#pragma unroll
      for (int r = 0; r < 4; ++r) s_gi[rb + r][col] = acc[r];
    }
    __syncthreads();  // gi dumped, buf reads complete

    // ======== phase 2: wait for h_t ========
    if (tid == 0) {
      const u32 target = (u32)(t + 1) * WG_PER_DIR;
      while (__hip_atomic_load(cnt, __ATOMIC_ACQUIRE, __HIP_MEMORY_SCOPE_AGENT) < target)
        __builtin_amdgcn_s_sleep(1);
    }
    __syncthreads();
    __threadfence();  // acquire: see remote hbuf writes

    // ======== phase 3: h_t staging + hh-GEMM ========
    const u16* hsrc = hbuf + ((size_t)(t & 1) * 2 + dir) * (BATCH * HDIM);
#pragma unroll
    for (int j = 0; j < 8; ++j) {
      const int c = tid + 256 * j;
      const int row = c >> 6;
      const int col = (c & 63) * 8;
      *(bf16x8*)(buf + row * LSTR + col) = *(const bf16x8*)(hsrc + row * HDIM + col);
    }
    __syncthreads();

    {
      f32x4 acc = {0.f, 0.f, 0.f, 0.f};
      const u16* ab = buf + arow * LSTR + koff;
#pragma unroll
      for (int kk = 0; kk < 16; ++kk) {
        bf16x8 a = *(const bf16x8*)(ab + kk * 32);
        acc = __builtin_amdgcn_mfma_f32_16x16x32_bf16(a, wfh[kk], acc, 0, 0, 0);
      }
      const int col = nt * 16 + (lane & 15);
      const int rb  = mt * 16 + ((lane >> 4) << 2);
#pragma unroll
      for (int r = 0; r < 4; ++r) s_gh[rb + r][col] = acc[r];
    }
    __syncthreads();

    // ======== phase 4: gates + state update (fp32) ========
    {
      const int b = tid >> 3, hh = tid & 7;
      const float rx = s_gi[b][hh]      + s_bih[hh];
      const float zx = s_gi[b][8 + hh]  + s_bih[8 + hh];
      const float nx = s_gi[b][16 + hh] + s_bih[16 + hh];
      const float rh = s_gh[b][hh]      + s_bhh[hh];
      const float zh = s_gh[b][8 + hh]  + s_bhh[8 + hh];
      const float nh = s_gh[b][16 + hh] + s_bhh[16 + hh];
      const float r = 1.f / (1.f + __expf(-(rx + rh)));
      const float z = 1.f / (1.f + __expf(-(zx + zh)));
      const float n = tanhf(nx + r * nh);
      const float hnew = (1.f - z) * n + z * s_hold[b][hh];
      s_hold[b][hh] = hnew;
      out[((size_t)t * BATCH + b) * (2 * HDIM) + dir * HDIM + hbase + hh] = hnew;
      hbuf[((size_t)((t + 1) & 1) * 2 + dir) * (BATCH * HDIM) + b * HDIM + hbase + hh] = f2bf(hnew);
    }

    // arrive: publish h_{t+1}
    __threadfence();
    __syncthreads();
    if (tid == 0) __hip_atomic_fetch_add(cnt, 1u, __ATOMIC_ACQ_REL, __HIP_MEMORY_SCOPE_AGENT);
  }

  // ---- final states: [1,2,B,H] appended after y ----
  {
    const int b = tid >> 3, hh = tid & 7;
    out[(size_t)T_LEN * BATCH * 2 * HDIM + (size_t)(dir * BATCH + b) * HDIM + hbase + hh] =
        s_hold[b][hh];
  }
}

extern "C" void kernel_launch(void* const* d_in, const int* in_sizes, int n_in,
                              void* d_out, int out_size, void* d_ws, size_t ws_size,
                              hipStream_t stream) {
  const float* x    = (const float*)d_in[0];
  const float* h0   = (const float*)d_in[1];
  const float* wihF = (const float*)d_in[2];
  const float* bihF = (const float*)d_in[3];
  const float* whhF = (const float*)d_in[4];
  const float* bhhF = (const float*)d_in[5];
  const float* wihR = (const float*)d_in[6];
  const float* bihR = (const float*)d_in[7];
  const float* whhR = (const float*)d_in[8];
  const float* bhhR = (const float*)d_in[9];

  const size_t NX = (size_t)T_LEN * BATCH * FDIM;   // 33,554,432 elements
  const size_t NW = (size_t)GDIM * FDIM;            // 786,432 elements

  char* ws   = (char*)d_ws;
  u16* xbf   = (u16*)ws;
  u16* wihFb = (u16*)(ws + NX * 2);
  u16* whhFb = wihFb + NW;
  u16* wihRb = whhFb + NW;
  u16* whhRb = wihRb + NW;
  u16* hbuf  = whhRb + NW;                          // 2*2*32*512 u16 = 128KB
  u32* cnt   = (u32*)((char*)(hbuf + 4 * BATCH * HDIM));

  hipMemsetAsync(cnt, 0, 256, stream);
  convert_kernel<<<2048, 256, 0, stream>>>(x,    xbf,   (int)(NX / 4));
  convert_kernel<<<256,  256, 0, stream>>>(wihF, wihFb, (int)(NW / 4));
  convert_kernel<<<256,  256, 0, stream>>>(whhF, whhFb, (int)(NW / 4));
  convert_kernel<<<256,  256, 0, stream>>>(wihR, wihRb, (int)(NW / 4));
  convert_kernel<<<256,  256, 0, stream>>>(whhR, whhRb, (int)(NW / 4));

  gru_scan<<<128, 256, 0, stream>>>(xbf, wihFb, whhFb, wihRb, whhRb,
                                    bihF, bhhF, bihR, bhhR,
                                    h0, hbuf, (float*)d_out, cnt);
}